// Round 10
// baseline (127.297 us; speedup 1.0000x reference)
//
#include <hip/hip_runtime.h>
#include <stdint.h>

#define S_LEN 2048
#define DMODEL 1024
#define NHEAD 16
#define DK 64
#define BATCH 2

typedef __attribute__((ext_vector_type(8))) short bf16x8;
typedef __attribute__((ext_vector_type(4))) float f32x4;

__device__ __forceinline__ unsigned short f2bf(float f) {
  union { float f; unsigned u; } x; x.f = f;
  unsigned u = x.u;
  return (unsigned short)((u + 0x7fffu + ((u >> 16) & 1u)) >> 16);
}

__device__ __forceinline__ uint cvt_pk_bf16(float a, float b) {
  uint r;
  asm("v_cvt_pk_bf16_f32 %0, %1, %2" : "=v"(r) : "v"(a), "v"(b));
  return r;
}

__device__ __forceinline__ void gload_lds16(const void* g, void* l) {
  __builtin_amdgcn_global_load_lds(
      (const __attribute__((address_space(1))) unsigned int*)g,
      (__attribute__((address_space(3))) unsigned int*)l, 16, 0, 0);
}

// Q scale: 1/sqrt(64) * log2(e)  (exp2-domain softmax)
#define QSCALE 0.18033688011112042f

// ------------- cast fp32 -> bf16 (x, weights) + RoPE table (fused) -------
__global__ __launch_bounds__(256) void cast_inputs(
    const float4* __restrict__ x,
    const float4* __restrict__ wq, const float4* __restrict__ wk,
    const float4* __restrict__ wv, const float4* __restrict__ wo,
    ushort4* __restrict__ xb, ushort4* __restrict__ wqkvb, ushort4* __restrict__ wob,
    const int* __restrict__ pos, float2* __restrict__ rope)
{
  int i = blockIdx.x * 256 + threadIdx.x;
  const int NCAST = (1 << 21);
  if (i < NCAST) {
    float4 v; ushort4* dst;
    if (i < (1 << 20)) {
      v = x[i]; dst = xb + i;
    } else {
      int j = i - (1 << 20);
      int wsel = j >> 18;
      int o = j & ((1 << 18) - 1);
      const float4* src = (wsel == 0) ? wq : (wsel == 1) ? wk : (wsel == 2) ? wv : wo;
      v = src[o];
      dst = (wsel < 3) ? (wqkvb + ((size_t)wsel << 18) + o) : (wob + o);
    }
    ushort4 r;
    r.x = f2bf(v.x); r.y = f2bf(v.y); r.z = f2bf(v.z); r.w = f2bf(v.w);
    *dst = r;
  } else {
    int idx = i - NCAST;
    if (idx < 4096 * 32) {
      int ps = idx >> 5;
      int fi = idx & 31;
      float p = (float)pos[ps];
      float freq = exp2f(-(float)fi * 0.41524101186092096f);
      float ang = p * freq;
      rope[idx] = make_float2(cosf(ang), sinf(ang));
    }
  }
}

// ---------------- QKV GEMM (bf16 in, fp32 acc), B^T weights ---------------
// N=3072 (Q|K|V): RoPE on Q (scaled QSCALE) and K -> [bh][s][64] bf16;
// V -> TRANSPOSED global layout [bh][d][s] bf16.
__global__ __launch_bounds__(256) void gemm_qkv(
    const ushort* __restrict__ A, const ushort* __restrict__ Bw,
    const float2* __restrict__ rope,
    ushort* __restrict__ Qb, ushort* __restrict__ Kb, ushort* __restrict__ Vg)
{
  constexpr int Kdim = 1024;
  __shared__ ushort At[128 * 64];
  __shared__ ushort Bt[128 * 64];
  const int bm = blockIdx.x & 31;
  const int bn = blockIdx.x >> 5;
  const int tid = threadIdx.x;
  const int w = tid >> 6, lane = tid & 63;
  const int wr = w >> 1, wc = w & 1;
  const int lrow = lane >> 3;
  const int lch = lane & 7;

  f32x4 acc[4][4];
#pragma unroll
  for (int i = 0; i < 4; ++i)
#pragma unroll
    for (int j = 0; j < 4; ++j) acc[i][j] = (f32x4){0.f, 0.f, 0.f, 0.f};

  const size_t abase = (size_t)(bm * 128) * Kdim;
  const size_t bbase = (size_t)(bn * 128) * Kdim;

  for (int kt = 0; kt < Kdim / 64; ++kt) {
#pragma unroll
    for (int inst = 0; inst < 4; ++inst) {
      int r = w * 32 + inst * 8 + lrow;
      int gc = lch ^ (r & 7);
      gload_lds16(A + abase + (size_t)r * Kdim + kt * 64 + gc * 8,
                  &At[(w * 32 + inst * 8) * 64]);
      gload_lds16(Bw + bbase + (size_t)r * Kdim + kt * 64 + gc * 8,
                  &Bt[(w * 32 + inst * 8) * 64]);
    }
    __syncthreads();
    __builtin_amdgcn_s_setprio(1);
#pragma unroll
    for (int kk = 0; kk < 2; ++kk) {
      bf16x8 af[4], bfv[4];
      int ch = kk * 4 + (lane >> 4);
#pragma unroll
      for (int fm = 0; fm < 4; ++fm) {
        int row = wr * 64 + fm * 16 + (lane & 15);
        af[fm] = *(const bf16x8*)&At[row * 64 + ((ch ^ (row & 7)) << 3)];
      }
#pragma unroll
      for (int fn = 0; fn < 4; ++fn) {
        int row = wc * 64 + fn * 16 + (lane & 15);
        bfv[fn] = *(const bf16x8*)&Bt[row * 64 + ((ch ^ (row & 7)) << 3)];
      }
#pragma unroll
      for (int fm = 0; fm < 4; ++fm)
#pragma unroll
        for (int fn = 0; fn < 4; ++fn)
          acc[fm][fn] = __builtin_amdgcn_mfma_f32_16x16x32_bf16(
              af[fm], bfv[fn], acc[fm][fn], 0, 0, 0);
    }
    __builtin_amdgcn_s_setprio(0);
    __syncthreads();
  }

  const int sel = bn >> 3;            // 0=Q 1=K 2=V (block-uniform)
  if (sel == 2) {
    // V: transposed global layout [bh][d][s]
#pragma unroll
    for (int fn = 0; fn < 4; ++fn) {
      int gn = bn * 128 + wc * 64 + fn * 16 + (lane & 15);
      int col = gn & 1023;
      int h = col >> 6, d = col & 63;
#pragma unroll
      for (int fm = 0; fm < 4; ++fm) {
        int gm0 = bm * 128 + wr * 64 + fm * 16 + ((lane >> 4) << 2);
        int b = gm0 >> 11, s0 = gm0 & 2047;
        uint lo = cvt_pk_bf16(acc[fm][fn][0], acc[fm][fn][1]);
        uint hi2 = cvt_pk_bf16(acc[fm][fn][2], acc[fm][fn][3]);
        uint2 val; val.x = lo; val.y = hi2;
        *(uint2*)(Vg + ((size_t)((b * NHEAD + h) * DK + d) * S_LEN) + s0) = val;
      }
    }
  } else {
    ushort* dst0 = (sel == 0) ? Qb : Kb;
#pragma unroll
    for (int fn = 0; fn < 4; ++fn) {
      int gn = bn * 128 + wc * 64 + fn * 16 + (lane & 15);
      int col = gn & 1023;
      int h = col >> 6, d = col & 63;
#pragma unroll
      for (int fm = 0; fm < 4; ++fm) {
        int gm0 = bm * 128 + wr * 64 + fm * 16 + ((lane >> 4) << 2);
#pragma unroll
        for (int j = 0; j < 4; ++j) {
          int gm = gm0 + j;
          float v = acc[fm][fn][j];
          float p = __shfl_xor(v, 1);
          float2 cs = rope[gm * 32 + (d >> 1)];
          float r = (d & 1) ? (v * cs.x + p * cs.y) : (v * cs.x - p * cs.y);
          if (sel == 0) r *= QSCALE;  // 1/8 * log2(e): exp2-domain softmax
          int b = gm >> 11, s = gm & 2047;
          dst0[((size_t)(b * NHEAD + h) * S_LEN + s) * DK + d] = f2bf(r);
        }
      }
    }
  }
}

// ---------------- Output GEMM: BM=64, BN=128 -> grid 512 = 2 blocks/CU -----
// (128x128 gave 256 blocks = 1 block/CU: latency-exposed, no co-resident
//  block to overlap the barrier drain. 64-row M-tiles double residency.)
__global__ __launch_bounds__(256) void gemm_out64(
    const ushort* __restrict__ A, const ushort* __restrict__ Bw,
    float* __restrict__ Out)
{
  constexpr int Kdim = 1024;
  __shared__ ushort At[64 * 64];
  __shared__ ushort Bt[128 * 64];
  const int bm = blockIdx.x & 63;       // 4096/64 = 64 M-tiles
  const int bn = blockIdx.x >> 6;       // 1024/128 = 8 N-tiles
  const int tid = threadIdx.x;
  const int w = tid >> 6, lane = tid & 63;
  const int wr = w >> 1, wc = w & 1;
  const int lrow = lane >> 3;
  const int lch = lane & 7;

  f32x4 acc[2][4];
#pragma unroll
  for (int i = 0; i < 2; ++i)
#pragma unroll
    for (int j = 0; j < 4; ++j) acc[i][j] = (f32x4){0.f, 0.f, 0.f, 0.f};

  const size_t abase = (size_t)(bm * 64) * Kdim;
  const size_t bbase = (size_t)(bn * 128) * Kdim;

  for (int kt = 0; kt < Kdim / 64; ++kt) {
#pragma unroll
    for (int inst = 0; inst < 2; ++inst) {
      int r = inst * 32 + w * 8 + lrow;
      int gc = lch ^ (r & 7);
      gload_lds16(A + abase + (size_t)r * Kdim + kt * 64 + gc * 8,
                  &At[(inst * 32 + w * 8) * 64]);
    }
#pragma unroll
    for (int inst = 0; inst < 4; ++inst) {
      int r = inst * 32 + w * 8 + lrow;
      int gc = lch ^ (r & 7);
      gload_lds16(Bw + bbase + (size_t)r * Kdim + kt * 64 + gc * 8,
                  &Bt[(inst * 32 + w * 8) * 64]);
    }
    __syncthreads();
    __builtin_amdgcn_s_setprio(1);
#pragma unroll
    for (int kk = 0; kk < 2; ++kk) {
      bf16x8 af[2], bfv[4];
      int ch = kk * 4 + (lane >> 4);
#pragma unroll
      for (int fm = 0; fm < 2; ++fm) {
        int row = wr * 32 + fm * 16 + (lane & 15);
        af[fm] = *(const bf16x8*)&At[row * 64 + ((ch ^ (row & 7)) << 3)];
      }
#pragma unroll
      for (int fn = 0; fn < 4; ++fn) {
        int row = wc * 64 + fn * 16 + (lane & 15);
        bfv[fn] = *(const bf16x8*)&Bt[row * 64 + ((ch ^ (row & 7)) << 3)];
      }
#pragma unroll
      for (int fm = 0; fm < 2; ++fm)
#pragma unroll
        for (int fn = 0; fn < 4; ++fn)
          acc[fm][fn] = __builtin_amdgcn_mfma_f32_16x16x32_bf16(
              af[fm], bfv[fn], acc[fm][fn], 0, 0, 0);
    }
    __builtin_amdgcn_s_setprio(0);
    __syncthreads();
  }

#pragma unroll
  for (int fn = 0; fn < 4; ++fn) {
    int gn = bn * 128 + wc * 64 + fn * 16 + (lane & 15);
#pragma unroll
    for (int fm = 0; fm < 2; ++fm) {
      int gm0 = bm * 64 + wr * 32 + fm * 16 + ((lane >> 4) << 2);
#pragma unroll
      for (int j = 0; j < 4; ++j)
        Out[(size_t)(gm0 + j) * 1024 + gn] = acc[fm][fn][j];
    }
  }
}

// ---------------- causal flash attention, swapped-QK^T, bf16 MFMA ----------
// R9 structure, split for 4 blocks/CU: grid 1024 = 32 bh * 16 pairs * 2 row-
// halves; block 256 = 4 waves * 16 rows. Waves 0,1 own rows [half*32+w*16) of
// qt=31-pair; waves 2,3 same rows of qt=pair (kv range is a shared prefix).
// One kv loop kt=0..31-pair, compute predicated kt<=qtw. LDS 40960 B -> 4
// blocks/CU = 16 waves/CU resident (vs R9's 8).
__global__ __launch_bounds__(256) void attn_kernel(
    const ushort* __restrict__ Qb, const ushort* __restrict__ Kb,
    const ushort* __restrict__ Vg, ushort* __restrict__ Ob)
{
  __shared__ ushort Kt[2][64 * 64];     // [kv][d] swizzled, double-buffered
  __shared__ ushort Vt[2][64 * 64];     // [d][kv] swizzled (from global V^T)
  __shared__ ushort Pt[4][16 * 64];     // per-wave P buffer [q][kv] swizzled
  const int tid = threadIdx.x;
  const int w = tid >> 6, lane = tid & 63;
  const int g = lane >> 4, q = lane & 15;
  const int ww = w & 1;
  const int bid = blockIdx.x;
  const int swz = (bid & 7) * 128 + (bid >> 3);  // XCD-chunked: 4 bh per XCD
  const int bh = swz >> 5;
  const int pair = (swz >> 1) & 15;
  const int half = swz & 1;
  const size_t kqbase = (size_t)bh * (S_LEN * DK);  // Q,K: [s][64]
  const size_t vbase  = (size_t)bh * (DK * S_LEN);  // V^T: [64][2048]
  const int b = bh >> 4, h = bh & 15;
  const int qtw = (w < 2) ? (31 - pair) : pair;     // this wave's q-tile
  const int ktmax = 31 - pair;                      // shared staging range
  const int qrow0 = qtw * 64 + half * 32 + ww * 16; // this wave's 16 rows
  ushort* Pw = Pt[w];
  uint* Pw32 = (uint*)Pw;

  bf16x8 qf[2];
  {
    const ushort* qp = Qb + kqbase + (size_t)(qrow0 + q) * DK + g * 8;
    qf[0] = *(const bf16x8*)qp;
    qf[1] = *(const bf16x8*)(qp + 32);
  }
  f32x4 oacc[4];
#pragma unroll
  for (int dt = 0; dt < 4; ++dt) oacc[dt] = (f32x4){0.f, 0.f, 0.f, 0.f};
  float m_r = -INFINITY, l_r = 0.f;

  // ---- stage tile 0 into buffer 0 (4 gloads/thread, 256 threads) ----
#define STAGE(buf_, kt_)                                                     \
  do {                                                                       \
    _Pragma("unroll") for (int pass = 0; pass < 2; ++pass) {                 \
      int r0 = pass * 32 + w * 8;                                            \
      int r = r0 + (lane >> 3);                                              \
      int gc = (lane & 7) ^ (r & 7);                                         \
      gload_lds16(Kb + kqbase + (size_t)((kt_) * 64 + r) * DK + gc * 8,      \
                  &Kt[buf_][r0 * 64]);                                       \
      gload_lds16(Vg + vbase + (size_t)r * S_LEN + (kt_) * 64 + gc * 8,      \
                  &Vt[buf_][r0 * 64]);                                       \
    }                                                                        \
  } while (0)

  STAGE(0, 0);
  __syncthreads();

  int cur = 0;
  for (int kt = 0; kt <= ktmax; ++kt) {
    // ---- prefetch next tile into other buffer (overlaps compute) ----
    if (kt < ktmax) STAGE(cur ^ 1, kt + 1);

    if (kt <= qtw) {
      // ---- S^T = K Q^T : lane owns column q (one q-row of S) ----
      f32x4 sacc[4];
#pragma unroll
      for (int ct = 0; ct < 4; ++ct) sacc[ct] = (f32x4){0.f, 0.f, 0.f, 0.f};
      __builtin_amdgcn_s_setprio(1);
#pragma unroll
      for (int kk = 0; kk < 2; ++kk) {
        int ch = kk * 4 + g;
#pragma unroll
        for (int ct = 0; ct < 4; ++ct) {
          int row = ct * 16 + q;
          bf16x8 kf = *(const bf16x8*)&Kt[cur][row * 64 + ((ch ^ (row & 7)) << 3)];
          sacc[ct] = __builtin_amdgcn_mfma_f32_16x16x32_bf16(kf, qf[kk], sacc[ct], 0, 0, 0);
        }
      }
      __builtin_amdgcn_s_setprio(0);

      if (kt == qtw) {                  // causal mask on diagonal tile
        int qa = qrow0 + q;
#pragma unroll
        for (int ct = 0; ct < 4; ++ct) {
#pragma unroll
          for (int j = 0; j < 4; ++j) {
            int kv = qtw * 64 + ct * 16 + g * 4 + j;
            if (kv > qa) sacc[ct][j] = -INFINITY;
          }
        }
      }

      // ---- online softmax: per-lane scalar state (lane owns one q-row) ----
      float mx = sacc[0][0];
#pragma unroll
      for (int ct = 0; ct < 4; ++ct)
#pragma unroll
        for (int j = 0; j < 4; ++j) mx = fmaxf(mx, sacc[ct][j]);
      mx = fmaxf(mx, __shfl_xor(mx, 16));
      mx = fmaxf(mx, __shfl_xor(mx, 32));
      if (mx > m_r + 8.0f) {            // defer-max: rescale only on growth
        float sc = exp2f(m_r - mx);
        m_r = mx;
        l_r *= sc;
#pragma unroll
        for (int dt = 0; dt < 4; ++dt)
#pragma unroll
          for (int j = 0; j < 4; ++j) oacc[dt][j] *= sc;
      }
      float p[4][4];
      float rs = 0.f;
#pragma unroll
      for (int ct = 0; ct < 4; ++ct)
#pragma unroll
        for (int j = 0; j < 4; ++j) {
          float e = exp2f(sacc[ct][j] - m_r);
          p[ct][j] = e; rs += e;
        }
      rs += __shfl_xor(rs, 16);
      rs += __shfl_xor(rs, 32);
      l_r += rs;

      // ---- P^T -> per-wave LDS (packed bf16 pairs along kv), reload as
      //      PV B-fragments (col=q, k-walk along kv) ----
#pragma unroll
      for (int ct = 0; ct < 4; ++ct)
#pragma unroll
        for (int i = 0; i < 2; ++i) {
          uint u = cvt_pk_bf16(p[ct][2 * i], p[ct][2 * i + 1]);
          int idx = 8 * ct + 2 * g + i;            // = kv/2
          Pw32[q * 32 + (((idx >> 2) ^ (q & 7)) << 2) + (idx & 3)] = u;
        }
      __builtin_amdgcn_s_setprio(1);
#pragma unroll
      for (int kk = 0; kk < 2; ++kk) {
        int ch = kk * 4 + g;
        bf16x8 pb = *(const bf16x8*)&Pw[q * 64 + ((ch ^ (q & 7)) << 3)];
#pragma unroll
        for (int dt = 0; dt < 4; ++dt) {
          int vr = dt * 16 + q;
          bf16x8 vf = *(const bf16x8*)&Vt[cur][vr * 64 + ((ch ^ (vr & 7)) << 3)];
          oacc[dt] = __builtin_amdgcn_mfma_f32_16x16x32_bf16(vf, pb, oacc[dt], 0, 0, 0);
        }
      }
      __builtin_amdgcn_s_setprio(0);
    }

    __syncthreads();                    // drains prefetch vmcnt + buf handoff
    cur ^= 1;
  }

  // ---- epilogue: O^T/l -> bf16, transpose via per-wave LDS, coalesced store
  float inv = 1.0f / l_r;
#pragma unroll
  for (int dt = 0; dt < 4; ++dt)
#pragma unroll
    for (int i = 0; i < 2; ++i) {
      uint u = cvt_pk_bf16(oacc[dt][2 * i] * inv, oacc[dt][2 * i + 1] * inv);
      int idx = dt * 8 + 2 * g + i;                // = d/2
      Pw32[q * 32 + (((idx >> 2) ^ (q & 7)) << 2) + (idx & 3)] = u;
    }
#pragma unroll
  for (int pass = 0; pass < 2; ++pass) {
    int qr = pass * 8 + (lane >> 3), c = lane & 7;
    bf16x8 vv = *(const bf16x8*)&Pw[qr * 64 + ((c ^ (qr & 7)) << 3)];
    *(bf16x8*)(Ob + ((size_t)(b * S_LEN) + qrow0 + qr) * DMODEL + h * DK + c * 8) = vv;
  }
#undef STAGE
}

// ---------------- launcher ----------------
extern "C" void kernel_launch(void* const* d_in, const int* in_sizes, int n_in,
                              void* d_out, int out_size, void* d_ws, size_t ws_size,
                              hipStream_t stream) {
  const float* x  = (const float*)d_in[0];
  const int* pos  = (const int*)d_in[1];
  const float* wq = (const float*)d_in[2];
  const float* wk = (const float*)d_in[3];
  const float* wv = (const float*)d_in[4];
  const float* wo = (const float*)d_in[5];
  float* out = (float*)d_out;

  char* ws = (char*)d_ws;
  ushort* xb    = (ushort*)(ws);                       //  8 MB
  ushort* wqkvb = (ushort*)(ws + (size_t)( 8u << 20)); //  6 MB
  ushort* wob   = (ushort*)(ws + (size_t)(14u << 20)); //  2 MB
  float2* rope  = (float2*)(ws + (size_t)(16u << 20)); //  1 MB
  ushort* Qb    = (ushort*)(ws + (size_t)(17u << 20)); //  8 MB [bh][s][64]
  ushort* Kb    = (ushort*)(ws + (size_t)(25u << 20)); //  8 MB [bh][s][64]
  ushort* Vg    = (ushort*)(ws + (size_t)(33u << 20)); //  8 MB [bh][64][s]  (V^T)
  ushort* Ob    = (ushort*)(ws + (size_t)(41u << 20)); //  8 MB [b][s][d]

  cast_inputs<<<8704, 256, 0, stream>>>((const float4*)x, (const float4*)wq,
      (const float4*)wk, (const float4*)wv, (const float4*)wo,
      (ushort4*)xb, (ushort4*)wqkvb, (ushort4*)wob, pos, rope);
  gemm_qkv<<<32 * 24, 256, 0, stream>>>(xb, wqkvb, rope, Qb, Kb, Vg);
  attn_kernel<<<1024, 256, 0, stream>>>(Qb, Kb, Vg, Ob);
  gemm_out64<<<512, 256, 0, stream>>>(Ob, wob, out);
}

// Round 12
// 119.174 us; speedup vs baseline: 1.0682x; 1.0682x over previous
//
#include <hip/hip_runtime.h>
#include <stdint.h>

#define S_LEN 2048
#define DMODEL 1024
#define NHEAD 16
#define DK 64
#define BATCH 2

typedef __attribute__((ext_vector_type(8))) short bf16x8;
typedef __attribute__((ext_vector_type(4))) float f32x4;

__device__ __forceinline__ unsigned short f2bf(float f) {
  union { float f; unsigned u; } x; x.f = f;
  unsigned u = x.u;
  return (unsigned short)((u + 0x7fffu + ((u >> 16) & 1u)) >> 16);
}

__device__ __forceinline__ uint cvt_pk_bf16(float a, float b) {
  uint r;
  asm("v_cvt_pk_bf16_f32 %0, %1, %2" : "=v"(r) : "v"(a), "v"(b));
  return r;
}

__device__ __forceinline__ void gload_lds16(const void* g, void* l) {
  __builtin_amdgcn_global_load_lds(
      (const __attribute__((address_space(1))) unsigned int*)g,
      (__attribute__((address_space(3))) unsigned int*)l, 16, 0, 0);
}

// Q scale: 1/sqrt(64) * log2(e)  (exp2-domain softmax)
#define QSCALE 0.18033688011112042f

// ------------- cast fp32 -> bf16 (x, weights) + RoPE table (fused) -------
__global__ __launch_bounds__(256) void cast_inputs(
    const float4* __restrict__ x,
    const float4* __restrict__ wq, const float4* __restrict__ wk,
    const float4* __restrict__ wv, const float4* __restrict__ wo,
    ushort4* __restrict__ xb, ushort4* __restrict__ wqkvb, ushort4* __restrict__ wob,
    const int* __restrict__ pos, float2* __restrict__ rope)
{
  int i = blockIdx.x * 256 + threadIdx.x;
  const int NCAST = (1 << 21);
  if (i < NCAST) {
    float4 v; ushort4* dst;
    if (i < (1 << 20)) {
      v = x[i]; dst = xb + i;
    } else {
      int j = i - (1 << 20);
      int wsel = j >> 18;
      int o = j & ((1 << 18) - 1);
      const float4* src = (wsel == 0) ? wq : (wsel == 1) ? wk : (wsel == 2) ? wv : wo;
      v = src[o];
      dst = (wsel < 3) ? (wqkvb + ((size_t)wsel << 18) + o) : (wob + o);
    }
    ushort4 r;
    r.x = f2bf(v.x); r.y = f2bf(v.y); r.z = f2bf(v.z); r.w = f2bf(v.w);
    *dst = r;
  } else {
    int idx = i - NCAST;
    if (idx < 4096 * 32) {
      int ps = idx >> 5;
      int fi = idx & 31;
      float p = (float)pos[ps];
      float freq = exp2f(-(float)fi * 0.41524101186092096f);
      float ang = p * freq;
      rope[idx] = make_float2(cosf(ang), sinf(ang));
    }
  }
}

// ---------------- QKV GEMM (bf16 in, fp32 acc), B^T weights ---------------
__global__ __launch_bounds__(256) void gemm_qkv(
    const ushort* __restrict__ A, const ushort* __restrict__ Bw,
    const float2* __restrict__ rope,
    ushort* __restrict__ Qb, ushort* __restrict__ Kb, ushort* __restrict__ Vg)
{
  constexpr int Kdim = 1024;
  __shared__ ushort At[128 * 64];
  __shared__ ushort Bt[128 * 64];
  const int bm = blockIdx.x & 31;
  const int bn = blockIdx.x >> 5;
  const int tid = threadIdx.x;
  const int w = tid >> 6, lane = tid & 63;
  const int wr = w >> 1, wc = w & 1;
  const int lrow = lane >> 3;
  const int lch = lane & 7;

  f32x4 acc[4][4];
#pragma unroll
  for (int i = 0; i < 4; ++i)
#pragma unroll
    for (int j = 0; j < 4; ++j) acc[i][j] = (f32x4){0.f, 0.f, 0.f, 0.f};

  const size_t abase = (size_t)(bm * 128) * Kdim;
  const size_t bbase = (size_t)(bn * 128) * Kdim;

  for (int kt = 0; kt < Kdim / 64; ++kt) {
#pragma unroll
    for (int inst = 0; inst < 4; ++inst) {
      int r = w * 32 + inst * 8 + lrow;
      int gc = lch ^ (r & 7);
      gload_lds16(A + abase + (size_t)r * Kdim + kt * 64 + gc * 8,
                  &At[(w * 32 + inst * 8) * 64]);
      gload_lds16(Bw + bbase + (size_t)r * Kdim + kt * 64 + gc * 8,
                  &Bt[(w * 32 + inst * 8) * 64]);
    }
    __syncthreads();
    __builtin_amdgcn_s_setprio(1);
#pragma unroll
    for (int kk = 0; kk < 2; ++kk) {
      bf16x8 af[4], bfv[4];
      int ch = kk * 4 + (lane >> 4);
#pragma unroll
      for (int fm = 0; fm < 4; ++fm) {
        int row = wr * 64 + fm * 16 + (lane & 15);
        af[fm] = *(const bf16x8*)&At[row * 64 + ((ch ^ (row & 7)) << 3)];
      }
#pragma unroll
      for (int fn = 0; fn < 4; ++fn) {
        int row = wc * 64 + fn * 16 + (lane & 15);
        bfv[fn] = *(const bf16x8*)&Bt[row * 64 + ((ch ^ (row & 7)) << 3)];
      }
#pragma unroll
      for (int fm = 0; fm < 4; ++fm)
#pragma unroll
        for (int fn = 0; fn < 4; ++fn)
          acc[fm][fn] = __builtin_amdgcn_mfma_f32_16x16x32_bf16(
              af[fm], bfv[fn], acc[fm][fn], 0, 0, 0);
    }
    __builtin_amdgcn_s_setprio(0);
    __syncthreads();
  }

  const int sel = bn >> 3;            // 0=Q 1=K 2=V (block-uniform)
  if (sel == 2) {
    // V: transposed global layout [bh][d][s]
#pragma unroll
    for (int fn = 0; fn < 4; ++fn) {
      int gn = bn * 128 + wc * 64 + fn * 16 + (lane & 15);
      int col = gn & 1023;
      int h = col >> 6, d = col & 63;
#pragma unroll
      for (int fm = 0; fm < 4; ++fm) {
        int gm0 = bm * 128 + wr * 64 + fm * 16 + ((lane >> 4) << 2);
        int b = gm0 >> 11, s0 = gm0 & 2047;
        uint lo = cvt_pk_bf16(acc[fm][fn][0], acc[fm][fn][1]);
        uint hi2 = cvt_pk_bf16(acc[fm][fn][2], acc[fm][fn][3]);
        uint2 val; val.x = lo; val.y = hi2;
        *(uint2*)(Vg + ((size_t)((b * NHEAD + h) * DK + d) * S_LEN) + s0) = val;
      }
    }
  } else {
    ushort* dst0 = (sel == 0) ? Qb : Kb;
#pragma unroll
    for (int fn = 0; fn < 4; ++fn) {
      int gn = bn * 128 + wc * 64 + fn * 16 + (lane & 15);
      int col = gn & 1023;
      int h = col >> 6, d = col & 63;
#pragma unroll
      for (int fm = 0; fm < 4; ++fm) {
        int gm0 = bm * 128 + wr * 64 + fm * 16 + ((lane >> 4) << 2);
#pragma unroll
        for (int j = 0; j < 4; ++j) {
          int gm = gm0 + j;
          float v = acc[fm][fn][j];
          float p = __shfl_xor(v, 1);
          float2 cs = rope[gm * 32 + (d >> 1)];
          float r = (d & 1) ? (v * cs.x + p * cs.y) : (v * cs.x - p * cs.y);
          if (sel == 0) r *= QSCALE;  // 1/8 * log2(e): exp2-domain softmax
          int b = gm >> 11, s = gm & 2047;
          dst0[((size_t)(b * NHEAD + h) * S_LEN + s) * DK + d] = f2bf(r);
        }
      }
    }
  }
}

// ---------------- Output GEMM: BM=64, BN=128 -> grid 512 = 2 blocks/CU -----
__global__ __launch_bounds__(256) void gemm_out64(
    const ushort* __restrict__ A, const ushort* __restrict__ Bw,
    float* __restrict__ Out)
{
  constexpr int Kdim = 1024;
  __shared__ ushort At[64 * 64];
  __shared__ ushort Bt[128 * 64];
  const int bm = blockIdx.x & 63;       // 4096/64 = 64 M-tiles
  const int bn = blockIdx.x >> 6;       // 1024/128 = 8 N-tiles
  const int tid = threadIdx.x;
  const int w = tid >> 6, lane = tid & 63;
  const int wr = w >> 1, wc = w & 1;
  const int lrow = lane >> 3;
  const int lch = lane & 7;

  f32x4 acc[2][4];
#pragma unroll
  for (int i = 0; i < 2; ++i)
#pragma unroll
    for (int j = 0; j < 4; ++j) acc[i][j] = (f32x4){0.f, 0.f, 0.f, 0.f};

  const size_t abase = (size_t)(bm * 64) * Kdim;
  const size_t bbase = (size_t)(bn * 128) * Kdim;

  for (int kt = 0; kt < Kdim / 64; ++kt) {
#pragma unroll
    for (int inst = 0; inst < 2; ++inst) {
      int r = inst * 32 + w * 8 + lrow;
      int gc = lch ^ (r & 7);
      gload_lds16(A + abase + (size_t)r * Kdim + kt * 64 + gc * 8,
                  &At[(inst * 32 + w * 8) * 64]);
    }
#pragma unroll
    for (int inst = 0; inst < 4; ++inst) {
      int r = inst * 32 + w * 8 + lrow;
      int gc = lch ^ (r & 7);
      gload_lds16(Bw + bbase + (size_t)r * Kdim + kt * 64 + gc * 8,
                  &Bt[(inst * 32 + w * 8) * 64]);
    }
    __syncthreads();
    __builtin_amdgcn_s_setprio(1);
#pragma unroll
    for (int kk = 0; kk < 2; ++kk) {
      bf16x8 af[2], bfv[4];
      int ch = kk * 4 + (lane >> 4);
#pragma unroll
      for (int fm = 0; fm < 2; ++fm) {
        int row = wr * 32 + fm * 16 + (lane & 15);
        af[fm] = *(const bf16x8*)&At[row * 64 + ((ch ^ (row & 7)) << 3)];
      }
#pragma unroll
      for (int fn = 0; fn < 4; ++fn) {
        int row = wc * 64 + fn * 16 + (lane & 15);
        bfv[fn] = *(const bf16x8*)&Bt[row * 64 + ((ch ^ (row & 7)) << 3)];
      }
#pragma unroll
      for (int fm = 0; fm < 2; ++fm)
#pragma unroll
        for (int fn = 0; fn < 4; ++fn)
          acc[fm][fn] = __builtin_amdgcn_mfma_f32_16x16x32_bf16(
              af[fm], bfv[fn], acc[fm][fn], 0, 0, 0);
    }
    __builtin_amdgcn_s_setprio(0);
    __syncthreads();
  }

#pragma unroll
  for (int fn = 0; fn < 4; ++fn) {
    int gn = bn * 128 + wc * 64 + fn * 16 + (lane & 15);
#pragma unroll
    for (int fm = 0; fm < 2; ++fm) {
      int gm0 = bm * 64 + wr * 32 + fm * 16 + ((lane >> 4) << 2);
#pragma unroll
      for (int j = 0; j < 4; ++j)
        Out[(size_t)(gm0 + j) * 1024 + gn] = acc[fm][fn][j];
    }
  }
}

// ---------------- causal flash attention, swapped-QK^T, bf16 MFMA ----------
// R9 champion structure RESTORED (measured 57.0 us): grid 512 = 32 bh * 16
// pairs; block 256 = 4 waves, wave w owns q-rows [qt*64+w*16, +16). Block
// processes q-tiles {pair, 31-pair} sequentially -> exactly 33 kv-tiles,
// fully balanced, zero redundant staging, independent blocks.
// R11 edit: l-sum kept as PER-LANE partial (rescale factor is row-uniform),
// cross-lane reduced ONCE in the epilogue -> saves 2 shuffles per kv-tile.
__global__ __launch_bounds__(256) void attn_kernel(
    const ushort* __restrict__ Qb, const ushort* __restrict__ Kb,
    const ushort* __restrict__ Vg, ushort* __restrict__ Ob)
{
  __shared__ ushort Kt[2][64 * 64];     // [kv][d] swizzled, double-buffered
  __shared__ ushort Vt[2][64 * 64];     // [d][kv] swizzled (from global V^T)
  __shared__ ushort Pt[4][16 * 64];     // per-wave P buffer [q][kv] swizzled
  const int tid = threadIdx.x;
  const int w = tid >> 6, lane = tid & 63;
  const int g = lane >> 4, q = lane & 15;
  const int bid = blockIdx.x;
  const int swz = (bid & 7) * 64 + (bid >> 3);   // XCD-chunked: same-bh together
  const int bh = swz >> 4, pair = swz & 15;
  const size_t kqbase = (size_t)bh * (S_LEN * DK);  // Q,K: [s][64]
  const size_t vbase  = (size_t)bh * (DK * S_LEN);  // V^T: [64][2048]
  const int b = bh >> 4, h = bh & 15;
  ushort* Pw = Pt[w];
  uint* Pw32 = (uint*)Pw;

  for (int t2 = 0; t2 < 2; ++t2) {
    const int qt = t2 ? (31 - pair) : pair;
    const int qrow0 = qt * 64 + w * 16;

    bf16x8 qf[2];
    {
      const ushort* qp = Qb + kqbase + (size_t)(qrow0 + q) * DK + g * 8;
      qf[0] = *(const bf16x8*)qp;
      qf[1] = *(const bf16x8*)(qp + 32);
    }
    f32x4 oacc[4];
#pragma unroll
    for (int dt = 0; dt < 4; ++dt) oacc[dt] = (f32x4){0.f, 0.f, 0.f, 0.f};
    float m_r = -INFINITY, l_r = 0.f;   // l_r: PER-LANE partial (own kv subset)

    // ---- stage tile 0 into buffer 0 ----
#pragma unroll
    for (int pass = 0; pass < 2; ++pass) {
      int r0 = pass * 32 + w * 8;
      int r = r0 + (lane >> 3);
      int gc = (lane & 7) ^ (r & 7);
      gload_lds16(Kb + kqbase + (size_t)r * DK + gc * 8, &Kt[0][r0 * 64]);
      gload_lds16(Vg + vbase + (size_t)r * S_LEN + gc * 8, &Vt[0][r0 * 64]);
    }
    __syncthreads();

    int cur = 0;
    for (int kt = 0; kt <= qt; ++kt) {
      // ---- prefetch next tile into other buffer (overlaps compute) ----
      if (kt < qt) {
        int nxt = cur ^ 1, ktn = kt + 1;
#pragma unroll
        for (int pass = 0; pass < 2; ++pass) {
          int r0 = pass * 32 + w * 8;
          int r = r0 + (lane >> 3);
          int gc = (lane & 7) ^ (r & 7);
          gload_lds16(Kb + kqbase + (size_t)(ktn * 64 + r) * DK + gc * 8,
                      &Kt[nxt][r0 * 64]);
          gload_lds16(Vg + vbase + (size_t)r * S_LEN + ktn * 64 + gc * 8,
                      &Vt[nxt][r0 * 64]);
        }
      }

      // ---- S^T = K Q^T : lane owns column q (one q-row of S) ----
      f32x4 sacc[4];
#pragma unroll
      for (int ct = 0; ct < 4; ++ct) sacc[ct] = (f32x4){0.f, 0.f, 0.f, 0.f};
      __builtin_amdgcn_s_setprio(1);
#pragma unroll
      for (int kk = 0; kk < 2; ++kk) {
        int ch = kk * 4 + g;
#pragma unroll
        for (int ct = 0; ct < 4; ++ct) {
          int row = ct * 16 + q;
          bf16x8 kf = *(const bf16x8*)&Kt[cur][row * 64 + ((ch ^ (row & 7)) << 3)];
          sacc[ct] = __builtin_amdgcn_mfma_f32_16x16x32_bf16(kf, qf[kk], sacc[ct], 0, 0, 0);
        }
      }
      __builtin_amdgcn_s_setprio(0);

      if (kt == qt) {                   // causal mask on diagonal tile
        int qa = qrow0 + q;
#pragma unroll
        for (int ct = 0; ct < 4; ++ct) {
#pragma unroll
          for (int j = 0; j < 4; ++j) {
            int kv = qt * 64 + ct * 16 + g * 4 + j;
            if (kv > qa) sacc[ct][j] = -INFINITY;
          }
        }
      }

      // ---- online softmax: m cross-lane (needed for PV consistency),
      //      l per-lane partial (reduced once in epilogue) ----
      float mx = sacc[0][0];
#pragma unroll
      for (int ct = 0; ct < 4; ++ct)
#pragma unroll
        for (int j = 0; j < 4; ++j) mx = fmaxf(mx, sacc[ct][j]);
      mx = fmaxf(mx, __shfl_xor(mx, 16));
      mx = fmaxf(mx, __shfl_xor(mx, 32));
      if (mx > m_r + 8.0f) {            // defer-max: rescale only on growth
        float sc = exp2f(m_r - mx);     // sc row-uniform -> per-lane l ok
        m_r = mx;
        l_r *= sc;
#pragma unroll
        for (int dt = 0; dt < 4; ++dt)
#pragma unroll
          for (int j = 0; j < 4; ++j) oacc[dt][j] *= sc;
      }
      float p[4][4];
      float rs = 0.f;
#pragma unroll
      for (int ct = 0; ct < 4; ++ct)
#pragma unroll
        for (int j = 0; j < 4; ++j) {
          float e = exp2f(sacc[ct][j] - m_r);
          p[ct][j] = e; rs += e;
        }
      l_r += rs;                        // per-lane partial; no shuffles here

      // ---- P^T -> per-wave LDS (packed bf16 pairs along kv), reload as
      //      PV B-fragments (col=q, k-walk along kv) ----
#pragma unroll
      for (int ct = 0; ct < 4; ++ct)
#pragma unroll
        for (int i = 0; i < 2; ++i) {
          uint u = cvt_pk_bf16(p[ct][2 * i], p[ct][2 * i + 1]);
          int idx = 8 * ct + 2 * g + i;            // = kv/2
          Pw32[q * 32 + (((idx >> 2) ^ (q & 7)) << 2) + (idx & 3)] = u;
        }
      __builtin_amdgcn_s_setprio(1);
#pragma unroll
      for (int kk = 0; kk < 2; ++kk) {
        int ch = kk * 4 + g;
        bf16x8 pb = *(const bf16x8*)&Pw[q * 64 + ((ch ^ (q & 7)) << 3)];
#pragma unroll
        for (int dt = 0; dt < 4; ++dt) {
          int vr = dt * 16 + q;
          bf16x8 vf = *(const bf16x8*)&Vt[cur][vr * 64 + ((ch ^ (vr & 7)) << 3)];
          oacc[dt] = __builtin_amdgcn_mfma_f32_16x16x32_bf16(vf, pb, oacc[dt], 0, 0, 0);
        }
      }
      __builtin_amdgcn_s_setprio(0);
      __syncthreads();                  // drains prefetch vmcnt + buffer handoff
      cur ^= 1;
    }

    // ---- epilogue: reduce l across the 4 g-lanes of each row, then
    //      O^T/l -> bf16, transpose via per-wave LDS, coalesced store ----
    float lt = l_r;
    lt += __shfl_xor(lt, 16);
    lt += __shfl_xor(lt, 32);
    float inv = 1.0f / lt;
#pragma unroll
    for (int dt = 0; dt < 4; ++dt)
#pragma unroll
      for (int i = 0; i < 2; ++i) {
        uint u = cvt_pk_bf16(oacc[dt][2 * i] * inv, oacc[dt][2 * i + 1] * inv);
        int idx = dt * 8 + 2 * g + i;              // = d/2
        Pw32[q * 32 + (((idx >> 2) ^ (q & 7)) << 2) + (idx & 3)] = u;
      }
#pragma unroll
    for (int pass = 0; pass < 2; ++pass) {
      int qr = pass * 8 + (lane >> 3), c = lane & 7;
      bf16x8 vv = *(const bf16x8*)&Pw[qr * 64 + ((c ^ (qr & 7)) << 3)];
      *(bf16x8*)(Ob + ((size_t)(b * S_LEN) + qrow0 + qr) * DMODEL + h * DK + c * 8) = vv;
    }
  }
}

// ---------------- launcher ----------------
extern "C" void kernel_launch(void* const* d_in, const int* in_sizes, int n_in,
                              void* d_out, int out_size, void* d_ws, size_t ws_size,
                              hipStream_t stream) {
  const float* x  = (const float*)d_in[0];
  const int* pos  = (const int*)d_in[1];
  const float* wq = (const float*)d_in[2];
  const float* wk = (const float*)d_in[3];
  const float* wv = (const float*)d_in[4];
  const float* wo = (const float*)d_in[5];
  float* out = (float*)d_out;

  char* ws = (char*)d_ws;
  ushort* xb    = (ushort*)(ws);                       //  8 MB
  ushort* wqkvb = (ushort*)(ws + (size_t)( 8u << 20)); //  6 MB
  ushort* wob   = (ushort*)(ws + (size_t)(14u << 20)); //  2 MB
  float2* rope  = (float2*)(ws + (size_t)(16u << 20)); //  1 MB
  ushort* Qb    = (ushort*)(ws + (size_t)(17u << 20)); //  8 MB [bh][s][64]
  ushort* Kb    = (ushort*)(ws + (size_t)(25u << 20)); //  8 MB [bh][s][64]
  ushort* Vg    = (ushort*)(ws + (size_t)(33u << 20)); //  8 MB [bh][64][s]  (V^T)
  ushort* Ob    = (ushort*)(ws + (size_t)(41u << 20)); //  8 MB [b][s][d]

  cast_inputs<<<8704, 256, 0, stream>>>((const float4*)x, (const float4*)wq,
      (const float4*)wk, (const float4*)wv, (const float4*)wo,
      (ushort4*)xb, (ushort4*)wqkvb, (ushort4*)wob, pos, rope);
  gemm_qkv<<<32 * 24, 256, 0, stream>>>(xb, wqkvb, rope, Qb, Kb, Vg);
  attn_kernel<<<512, 256, 0, stream>>>(Qb, Kb, Vg, Ob);
  gemm_out64<<<512, 256, 0, stream>>>(Ob, wob, out);
}